// Round 7
// baseline (4024.361 us; speedup 1.0000x reference)
//
#include <hip/hip_runtime.h>
#include <hip/hip_cooperative_groups.h>
#include <math.h>

namespace cg = cooperative_groups;

#define B_   256
#define H_   512
#define V_   16000
#define M_   32
#define SOS_ 1
#define EOS_ 2
#define INV_SCALE (1.0f/2048.0f)
#define NTHR 256

typedef _Float16 half_t;
typedef _Float16 f16x8 __attribute__((ext_vector_type(8)));
typedef _Float16 f16x4 __attribute__((ext_vector_type(4)));
typedef float    f32x4 __attribute__((ext_vector_type(4)));

struct Params {
    const float *sem_f, *emb;
    const float *b_ih0, *b_hh0, *b_ih1, *b_hh1, *fc_b;
    const float *W_ih0, *W_hh0, *W_ih1, *W_hh1, *fc_W;
    float *decoded, *logits, *mask;
    float *PRE, *h0, *h1;
    half_t *h0a, *h0b, *h1a, *h1b, *xa, *xb;
    float *pmax; int *pidx; int *inputs; int *finished;
    half_t *wi0a, *wi0b, *wh0a, *wh0b, *wi1a, *wi1b, *wh1a, *wh1b, *fca, *fcbp;
};

__device__ __forceinline__ void split_f32(float x, half_t& a, half_t& b) {
    a = (half_t)x;
    b = (half_t)((x - (float)a) * 2048.0f);
}

__device__ __forceinline__ void split_plane_dev(const float* __restrict__ src,
    half_t* __restrict__ hi, half_t* __restrict__ lo, int n4, int gidx, int gst)
{
    for (int i = gidx; i < n4; i += gst) {
        const float4 v = ((const float4*)src)[i];
        f16x4 a, b; half_t t0, t1;
        split_f32(v.x, t0, t1); a[0] = t0; b[0] = t1;
        split_f32(v.y, t0, t1); a[1] = t0; b[1] = t1;
        split_f32(v.z, t0, t1); a[2] = t0; b[2] = t1;
        split_f32(v.w, t0, t1); a[3] = t0; b[3] = t1;
        ((f16x4*)hi)[i] = a; ((f16x4*)lo)[i] = b;
    }
}

// ---------------------------------------------------------------------------
// Unified GEMM tile: OUT[128 rows x 64 cols], K=512, fp16x2 3-pass MFMA.
// 4 waves as 2x2; wave = 64 rows x 32 cols; rf=4, cf=2.
// A planes read from global; W tile (64 x 32-K slice, both planes) staged in LDS.
// ---------------------------------------------------------------------------

// ----- GRU variant: ct in [0,48) (ct<24 -> ih), rt in [0,2). Epilogue -> PRE.
__device__ void gru_tile(int ct, int rt,
    const half_t* __restrict__ Aia, const half_t* __restrict__ Aib,
    const half_t* __restrict__ Aha, const half_t* __restrict__ Ahb,
    const half_t* __restrict__ Wia, const half_t* __restrict__ Wib,
    const half_t* __restrict__ Wha, const half_t* __restrict__ Whb,
    const float* __restrict__ b_ih, const float* __restrict__ b_hh,
    float* __restrict__ PRE,
    half_t (*W0s)[40], half_t (*W1s)[40])
{
    const bool is_ih = (ct < 24);
    const int wrow0 = (is_ih ? ct : ct - 24) * 64;   // W/bias row offset
    const int row0  = rt * 128;
    const float*  bias = is_ih ? b_ih : b_hh;
    const half_t* Aa = is_ih ? Aia : Aha;
    const half_t* Ab = is_ih ? Aib : Ahb;
    const half_t* W0 = is_ih ? Wia : Wha;
    const half_t* W1 = is_ih ? Wib : Whb;

    const int tid  = threadIdx.x;
    const int wv   = tid >> 6;
    const int wr   = wv >> 1, wc = wv & 1;
    const int lane = tid & 63;
    const int ll   = lane & 15, lg = lane >> 4;
    const int sc   = tid >> 2;             // 0..63 staged W row
    const int sk   = (tid & 3) * 8;        // 0,8,16,24
    const half_t* wp0 = W0 + (size_t)(wrow0 + sc) * H_ + sk;
    const half_t* wp1 = W1 + (size_t)(wrow0 + sc) * H_ + sk;

    f32x4 accM[4][2] = {};
    f32x4 accC[4][2] = {};

    for (int k0 = 0; k0 < H_; k0 += 32) {
        const f16x8 s0 = *(const f16x8*)(wp0 + k0);
        const f16x8 s1 = *(const f16x8*)(wp1 + k0);
        __syncthreads();
        *(f16x8*)&W0s[sc][sk] = s0;
        *(f16x8*)&W1s[sc][sk] = s1;
        __syncthreads();

        f16x8 a0[4], a1[4];
#pragma unroll
        for (int rf = 0; rf < 4; ++rf) {
            const size_t off = ((size_t)(row0 + 64*wr + 16*rf + ll) << 9) + k0 + (lg << 3);
            a0[rf] = *(const f16x8*)(Aa + off);
            a1[rf] = *(const f16x8*)(Ab + off);
        }
#pragma unroll
        for (int cf = 0; cf < 2; ++cf) {
            const int c = 32*wc + 16*cf + ll;
            const f16x8 b0 = *(const f16x8*)&W0s[c][lg << 3];
            const f16x8 b1 = *(const f16x8*)&W1s[c][lg << 3];
#pragma unroll
            for (int rf = 0; rf < 4; ++rf) {
                accM[rf][cf] = __builtin_amdgcn_mfma_f32_16x16x32_f16(a0[rf], b0, accM[rf][cf], 0,0,0);
                accC[rf][cf] = __builtin_amdgcn_mfma_f32_16x16x32_f16(a0[rf], b1, accC[rf][cf], 0,0,0);
                accC[rf][cf] = __builtin_amdgcn_mfma_f32_16x16x32_f16(a1[rf], b0, accC[rf][cf], 0,0,0);
            }
        }
    }

#pragma unroll
    for (int cf = 0; cf < 2; ++cf) {
        const int cl = 32*wc + 16*cf + ll;           // 0..63
        const float bv = bias[wrow0 + cl];
        const int c = ct * 64 + cl;                  // 0..3071
#pragma unroll
        for (int rf = 0; rf < 4; ++rf) {
#pragma unroll
            for (int r = 0; r < 4; ++r) {
                const int row = row0 + 64*wr + 16*rf + lg*4 + r;
                PRE[(size_t)row * 3072 + c] = accM[rf][cf][r] + accC[rf][cf][r] * INV_SCALE + bv;
            }
        }
    }
}

// ----- FC variant: ct in [0,250), rt in [0,2). Epilogue -> logits + argmax partials.
__device__ void fc_tile(int ct, int rt,
    const half_t* __restrict__ Aa, const half_t* __restrict__ Ab,
    const half_t* __restrict__ W0, const half_t* __restrict__ W1,
    const float* __restrict__ fcb, const int* __restrict__ finished,
    float* __restrict__ logits, float* __restrict__ pmax, int* __restrict__ pidx,
    int t, half_t (*W0s)[40], half_t (*W1s)[40], float (*pmS)[2], int (*piS)[2])
{
    const int col0 = ct * 64;
    const int row0 = rt * 128;
    const int tid  = threadIdx.x;
    const int wv   = tid >> 6;
    const int wr   = wv >> 1, wc = wv & 1;
    const int lane = tid & 63;
    const int ll   = lane & 15, lg = lane >> 4;
    const int sc   = tid >> 2;
    const int sk   = (tid & 3) * 8;
    const half_t* wp0 = W0 + (size_t)(col0 + sc) * H_ + sk;
    const half_t* wp1 = W1 + (size_t)(col0 + sc) * H_ + sk;

    f32x4 accM[4][2] = {};
    f32x4 accC[4][2] = {};

    for (int k0 = 0; k0 < H_; k0 += 32) {
        const f16x8 s0 = *(const f16x8*)(wp0 + k0);
        const f16x8 s1 = *(const f16x8*)(wp1 + k0);
        __syncthreads();
        *(f16x8*)&W0s[sc][sk] = s0;
        *(f16x8*)&W1s[sc][sk] = s1;
        __syncthreads();

        f16x8 a0[4], a1[4];
#pragma unroll
        for (int rf = 0; rf < 4; ++rf) {
            const size_t off = ((size_t)(row0 + 64*wr + 16*rf + ll) << 9) + k0 + (lg << 3);
            a0[rf] = *(const f16x8*)(Aa + off);
            a1[rf] = *(const f16x8*)(Ab + off);
        }
#pragma unroll
        for (int cf = 0; cf < 2; ++cf) {
            const int c = 32*wc + 16*cf + ll;
            const f16x8 b0 = *(const f16x8*)&W0s[c][lg << 3];
            const f16x8 b1 = *(const f16x8*)&W1s[c][lg << 3];
#pragma unroll
            for (int rf = 0; rf < 4; ++rf) {
                accM[rf][cf] = __builtin_amdgcn_mfma_f32_16x16x32_f16(a0[rf], b0, accM[rf][cf], 0,0,0);
                accC[rf][cf] = __builtin_amdgcn_mfma_f32_16x16x32_f16(a0[rf], b1, accC[rf][cf], 0,0,0);
                accC[rf][cf] = __builtin_amdgcn_mfma_f32_16x16x32_f16(a1[rf], b0, accC[rf][cf], 0,0,0);
            }
        }
    }

    int fin[4][4];
    float bvv[4][4];
    int   bii[4][4];
#pragma unroll
    for (int rf = 0; rf < 4; ++rf)
#pragma unroll
        for (int r = 0; r < 4; ++r) {
            fin[rf][r] = finished[row0 + 64*wr + 16*rf + lg*4 + r];
            bvv[rf][r] = -INFINITY; bii[rf][r] = 0x7fffffff;
        }

#pragma unroll
    for (int cf = 0; cf < 2; ++cf) {
        const int col = col0 + 32*wc + 16*cf + ll;
        const float bv = fcb[col];
#pragma unroll
        for (int rf = 0; rf < 4; ++rf) {
#pragma unroll
            for (int r = 0; r < 4; ++r) {
                const int row = row0 + 64*wr + 16*rf + lg*4 + r;
                const float raw = accM[rf][cf][r] + accC[rf][cf][r] * INV_SCALE + bv;
                logits[((size_t)row * M_ + t) * V_ + col] = fin[rf][r] ? 0.0f : raw;
                if (raw > bvv[rf][r]) { bvv[rf][r] = raw; bii[rf][r] = col; } // cf asc
            }
        }
    }

#pragma unroll
    for (int rf = 0; rf < 4; ++rf) {
#pragma unroll
        for (int r = 0; r < 4; ++r) {
            float v = bvv[rf][r]; int ix = bii[rf][r];
#pragma unroll
            for (int m = 1; m < 16; m <<= 1) {
                const float ov = __shfl_xor(v, m);
                const int   oi = __shfl_xor(ix, m);
                if (ov > v || (ov == v && oi < ix)) { v = ov; ix = oi; }
            }
            if (ll == 0) {
                const int lr = 64*wr + 16*rf + lg*4 + r;   // 0..127
                pmS[lr][wc] = v; piS[lr][wc] = ix;
            }
        }
    }
    __syncthreads();
    if (tid < 128) {
        float v = pmS[tid][0]; int ix = piS[tid][0];
        const float v2 = pmS[tid][1]; const int i2 = piS[tid][1];
        if (v2 > v || (v2 == v && i2 < ix)) { v = v2; ix = i2; }
        pmax[(size_t)(row0 + tid) * 256 + ct] = v;
        pidx[(size_t)(row0 + tid) * 256 + ct] = ix;
    }
    __syncthreads();
}

// ----- gate elementwise (one h element) -----
__device__ __forceinline__ void gate_elem(const float* __restrict__ PRE,
    float* __restrict__ h, half_t* __restrict__ ha, half_t* __restrict__ hb,
    const int* __restrict__ finished, int idx)
{
    const int b = idx >> 9;
    const int j = idx & 511;
    if (finished[b]) return;
    const float* p = PRE + (size_t)b * 3072;
    const float ir = p[j],        iz = p[512 + j],  in_ = p[1024 + j];
    const float hr = p[1536 + j], hz = p[2048 + j], hn  = p[2560 + j];
    const float r = 1.0f / (1.0f + expf(-(ir + hr)));
    const float z = 1.0f / (1.0f + expf(-(iz + hz)));
    const float n = tanhf(in_ + r * hn);
    const float hv = (1.0f - z) * n + z * h[idx];
    h[idx] = hv;
    half_t a, bb; split_f32(hv, a, bb);
    ha[idx] = a; hb[idx] = bb;
}

// ----- finalize one row (256 threads) -----
__device__ void finalize_row(int b, const Params& p, int t,
                             float* sv, int* si, int* s_tok)
{
    const int tid = threadIdx.x;
    float v = -INFINITY; int ix = 0x7fffffff;
    if (tid < 250) { v = p.pmax[(size_t)b * 256 + tid]; ix = p.pidx[(size_t)b * 256 + tid]; }
    sv[tid] = v; si[tid] = ix;
    __syncthreads();
    for (int s = 128; s > 0; s >>= 1) {
        if (tid < s) {
            const float v2 = sv[tid + s]; const int i2 = si[tid + s];
            if (v2 > sv[tid] || (v2 == sv[tid] && i2 < si[tid])) { sv[tid] = v2; si[tid] = i2; }
        }
        __syncthreads();
    }
    if (tid == 0) {
        const int fin = p.finished[b];
        const int dec = si[0];
        p.decoded[b * M_ + t] = fin ? -1.0f : (float)dec;
        p.mask   [b * M_ + t] = fin ? 0.0f : 1.0f;
        int tok;
        if (!fin) { p.inputs[b] = dec; if (dec == EOS_) p.finished[b] = 1; tok = dec; }
        else tok = p.inputs[b];
        *s_tok = tok;
    }
    __syncthreads();
    const int tok = *s_tok;
    for (int j = tid; j < H_; j += NTHR) {
        const float v2 = p.emb[(size_t)tok * H_ + j];
        half_t a, bb; split_f32(v2, a, bb);
        p.xa[b * H_ + j] = a; p.xb[b * H_ + j] = bb;
    }
    __syncthreads();
}

// ---------------------------------------------------------------------------
// Persistent cooperative kernel: preamble + 32 steps, grid-stride phases.
// ---------------------------------------------------------------------------
__global__ __launch_bounds__(NTHR, 2)
void scan_coop(Params p)
{
    cg::grid_group grid = cg::this_grid();

    __shared__ half_t W0s[64][40];
    __shared__ half_t W1s[64][40];
    __shared__ float  red_f[256];
    __shared__ int    red_i[256];
    __shared__ int    s_tok;

    const int nblk = gridDim.x;
    const int blk  = blockIdx.x;
    const int tid  = threadIdx.x;
    const int gidx = blk * NTHR + tid;
    const int gst  = nblk * NTHR;

    // preamble: weight splits + state init
    split_plane_dev(p.W_ih0, p.wi0a, p.wi0b, (1536*512)/4, gidx, gst);
    split_plane_dev(p.W_hh0, p.wh0a, p.wh0b, (1536*512)/4, gidx, gst);
    split_plane_dev(p.W_ih1, p.wi1a, p.wi1b, (1536*512)/4, gidx, gst);
    split_plane_dev(p.W_hh1, p.wh1a, p.wh1b, (1536*512)/4, gidx, gst);
    split_plane_dev(p.fc_W,  p.fca,  p.fcbp, (V_*H_)/4,    gidx, gst);
    for (int i = gidx; i < B_ * H_; i += gst) {
        const float v = p.sem_f[i];
        p.h0[i] = v; p.h1[i] = v;
        half_t a, b; split_f32(v, a, b);
        p.h0a[i] = a; p.h0b[i] = b;
        p.h1a[i] = a; p.h1b[i] = b;
        const int j = i & (H_ - 1);
        const float xv = p.emb[SOS_ * H_ + j];
        half_t c, d; split_f32(xv, c, d);
        p.xa[i] = c; p.xb[i] = d;
    }
    for (int i = gidx; i < B_; i += gst) { p.inputs[i] = SOS_; p.finished[i] = 0; }
    grid.sync();

    for (int t = 0; t < M_; ++t) {
        // P1: GRU-0 pre-activations (96 tiles: ct 48 x rt 2)
        for (int tile = blk; tile < 96; tile += nblk)
            gru_tile(tile % 48, tile / 48, p.xa, p.xb, p.h0a, p.h0b,
                     p.wi0a, p.wi0b, p.wh0a, p.wh0b, p.b_ih0, p.b_hh0, p.PRE, W0s, W1s);
        grid.sync();
        // P2: gate 0
        for (int i = gidx; i < B_ * H_; i += gst)
            gate_elem(p.PRE, p.h0, p.h0a, p.h0b, p.finished, i);
        grid.sync();
        // P3: GRU-1 pre-activations
        for (int tile = blk; tile < 96; tile += nblk)
            gru_tile(tile % 48, tile / 48, p.h0a, p.h0b, p.h1a, p.h1b,
                     p.wi1a, p.wi1b, p.wh1a, p.wh1b, p.b_ih1, p.b_hh1, p.PRE, W0s, W1s);
        grid.sync();
        // P4: gate 1
        for (int i = gidx; i < B_ * H_; i += gst)
            gate_elem(p.PRE, p.h1, p.h1a, p.h1b, p.finished, i);
        grid.sync();
        // P5: FC + logits + argmax partials (500 tiles: ct 250 x rt 2)
        for (int tile = blk; tile < 500; tile += nblk)
            fc_tile(tile % 250, tile / 250, p.h1a, p.h1b, p.fca, p.fcbp, p.fc_b,
                    p.finished, p.logits, p.pmax, p.pidx, t, W0s, W1s,
                    (float(*)[2])red_f, (int(*)[2])red_i);
        grid.sync();
        // P6: finalize + next-x gather
        for (int b = blk; b < B_; b += nblk)
            finalize_row(b, p, t, red_f, red_i, &s_tok);
        grid.sync();
    }
}

// ---------------------------------------------------------------------------
// Fallback multi-kernel path (same math, separate launches)
// ---------------------------------------------------------------------------
__global__ __launch_bounds__(256)
void split_weights_k(const float* __restrict__ src, half_t* __restrict__ hi,
                     half_t* __restrict__ lo, int n4)
{
    const int i = blockIdx.x * 256 + threadIdx.x;
    if (i >= n4) return;
    const float4 v = ((const float4*)src)[i];
    f16x4 a, b; half_t t0, t1;
    split_f32(v.x, t0, t1); a[0] = t0; b[0] = t1;
    split_f32(v.y, t0, t1); a[1] = t0; b[1] = t1;
    split_f32(v.z, t0, t1); a[2] = t0; b[2] = t1;
    split_f32(v.w, t0, t1); a[3] = t0; b[3] = t1;
    ((f16x4*)hi)[i] = a; ((f16x4*)lo)[i] = b;
}

__global__ __launch_bounds__(256)
void init_k(Params p)
{
    const int i = blockIdx.x * 256 + threadIdx.x;
    if (i < B_ * H_) {
        const float v = p.sem_f[i];
        p.h0[i] = v; p.h1[i] = v;
        half_t a, b; split_f32(v, a, b);
        p.h0a[i] = a; p.h0b[i] = b;
        p.h1a[i] = a; p.h1b[i] = b;
        const int j = i & (H_ - 1);
        const float xv = p.emb[SOS_ * H_ + j];
        half_t c, d; split_f32(xv, c, d);
        p.xa[i] = c; p.xb[i] = d;
    }
    if (i < B_) { p.inputs[i] = SOS_; p.finished[i] = 0; }
}

__global__ __launch_bounds__(256)
void gru_k(const half_t* Aia, const half_t* Aib, const half_t* Aha, const half_t* Ahb,
           const half_t* Wia, const half_t* Wib, const half_t* Wha, const half_t* Whb,
           const float* b_ih, const float* b_hh, float* PRE)
{
    __shared__ half_t W0s[64][40];
    __shared__ half_t W1s[64][40];
    gru_tile(blockIdx.x, blockIdx.y, Aia, Aib, Aha, Ahb,
             Wia, Wib, Wha, Whb, b_ih, b_hh, PRE, W0s, W1s);
}

__global__ __launch_bounds__(256)
void gate_k(const float* PRE, float* h, half_t* ha, half_t* hb, const int* finished)
{
    gate_elem(PRE, h, ha, hb, finished, blockIdx.x * 256 + threadIdx.x);
}

__global__ __launch_bounds__(256)
void fc_k(const half_t* Aa, const half_t* Ab, const half_t* W0, const half_t* W1,
          const float* fcb, const int* finished, float* logits,
          float* pmax, int* pidx, int t)
{
    __shared__ half_t W0s[64][40];
    __shared__ half_t W1s[64][40];
    __shared__ float  pmS[128][2];
    __shared__ int    piS[128][2];
    fc_tile(blockIdx.x, blockIdx.y, Aa, Ab, W0, W1, fcb, finished,
            logits, pmax, pidx, t, W0s, W1s, pmS, piS);
}

__global__ __launch_bounds__(256)
void finalize_k(Params p, int t)
{
    __shared__ float sv[256];
    __shared__ int   si[256];
    __shared__ int   s_tok;
    finalize_row(blockIdx.x, p, t, sv, si, &s_tok);
}

// ---------------------------------------------------------------------------
extern "C" void kernel_launch(void* const* d_in, const int* in_sizes, int n_in,
                              void* d_out, int out_size, void* d_ws, size_t ws_size,
                              hipStream_t stream)
{
    Params p;
    p.sem_f = (const float*)d_in[0];
    p.emb   = (const float*)d_in[1];
    p.W_ih0 = (const float*)d_in[2];
    p.W_hh0 = (const float*)d_in[3];
    p.b_ih0 = (const float*)d_in[4];
    p.b_hh0 = (const float*)d_in[5];
    p.W_ih1 = (const float*)d_in[6];
    p.W_hh1 = (const float*)d_in[7];
    p.b_ih1 = (const float*)d_in[8];
    p.b_hh1 = (const float*)d_in[9];
    p.fc_W  = (const float*)d_in[10];
    p.fc_b  = (const float*)d_in[11];

    float* out = (float*)d_out;
    p.decoded = out;
    p.logits  = out + (size_t)B_ * M_;
    p.mask    = out + (size_t)B_ * M_ + (size_t)B_ * M_ * V_;

    float* ws = (float*)d_ws;
    p.PRE  = ws;                              // 786432
    p.h0   = ws + 786432;                     // 131072
    p.h1   = ws + 917504;                     // 131072
    p.h0a  = (half_t*)(ws + 1048576);         // 65536 f each
    p.h0b  = (half_t*)(ws + 1114112);
    p.h1a  = (half_t*)(ws + 1179648);
    p.h1b  = (half_t*)(ws + 1245184);
    p.xa   = (half_t*)(ws + 1310720);
    p.xb   = (half_t*)(ws + 1376256);
    p.pmax = ws + 1441792;                    // 256*256 = 65536
    p.pidx = (int*)(ws + 1507328);            // 65536
    p.inputs   = (int*)(ws + 1572864);        // 256
    p.finished = (int*)(ws + 1573120);        // 256
    p.wi0a = (half_t*)(ws + 1573376);         // each GRU plane 393216 f
    p.wi0b = (half_t*)(ws + 1966592);
    p.wh0a = (half_t*)(ws + 2359808);
    p.wh0b = (half_t*)(ws + 2753024);
    p.wi1a = (half_t*)(ws + 3146240);
    p.wi1b = (half_t*)(ws + 3539456);
    p.wh1a = (half_t*)(ws + 3932672);
    p.wh1b = (half_t*)(ws + 4325888);
    p.fca  = (half_t*)(ws + 4719104);         // 4096000 f each
    p.fcbp = (half_t*)(ws + 8815104);
    // total 12911104 floats = 51.6 MB

    // ---- try the cooperative persistent kernel, occupancy-sized ----
    int occ = 0;
    hipError_t oe = hipOccupancyMaxActiveBlocksPerMultiprocessor(&occ, scan_coop, NTHR, 0);
    hipError_t le = hipErrorUnknown;
    if (oe == hipSuccess && occ >= 1) {
        const int nblk = (occ >= 2) ? 512 : 256;
        void* args[] = { &p };
        le = hipLaunchCooperativeKernel((const void*)scan_coop, dim3(nblk), dim3(NTHR),
                                        args, 0, stream);
    }
    if (le == hipSuccess) return;

    // ---- fallback: multi-kernel sequence (identical math) ----
    const int nGru4 = (1536 * 512) / 4;
    const int nFc4  = (V_ * H_) / 4;
    split_weights_k<<<(nGru4 + 255) / 256, 256, 0, stream>>>(p.W_ih0, p.wi0a, p.wi0b, nGru4);
    split_weights_k<<<(nGru4 + 255) / 256, 256, 0, stream>>>(p.W_hh0, p.wh0a, p.wh0b, nGru4);
    split_weights_k<<<(nGru4 + 255) / 256, 256, 0, stream>>>(p.W_ih1, p.wi1a, p.wi1b, nGru4);
    split_weights_k<<<(nGru4 + 255) / 256, 256, 0, stream>>>(p.W_hh1, p.wh1a, p.wh1b, nGru4);
    split_weights_k<<<(nFc4 + 255) / 256, 256, 0, stream>>>(p.fc_W, p.fca, p.fcbp, nFc4);
    init_k<<<(B_ * H_ + 255) / 256, 256, 0, stream>>>(p);

    const dim3 gruGrid(48, 2);
    const dim3 fcGrid(250, 2);
    for (int t = 0; t < M_; ++t) {
        gru_k<<<gruGrid, 256, 0, stream>>>(p.xa, p.xb, p.h0a, p.h0b,
            p.wi0a, p.wi0b, p.wh0a, p.wh0b, p.b_ih0, p.b_hh0, p.PRE);
        gate_k<<<(B_ * H_) / 256, 256, 0, stream>>>(p.PRE, p.h0, p.h0a, p.h0b, p.finished);
        gru_k<<<gruGrid, 256, 0, stream>>>(p.h0a, p.h0b, p.h1a, p.h1b,
            p.wi1a, p.wi1b, p.wh1a, p.wh1b, p.b_ih1, p.b_hh1, p.PRE);
        gate_k<<<(B_ * H_) / 256, 256, 0, stream>>>(p.PRE, p.h1, p.h1a, p.h1b, p.finished);
        fc_k<<<fcGrid, 256, 0, stream>>>(p.h1a, p.h1b, p.fca, p.fcbp, p.fc_b,
            p.finished, p.logits, p.pmax, p.pidx, t);
        finalize_k<<<B_, 256, 0, stream>>>(p, t);
    }
}

// Round 8
// 4023.161 us; speedup vs baseline: 1.0003x; 1.0003x over previous
//
#include <hip/hip_runtime.h>
#include <hip/hip_cooperative_groups.h>
#include <math.h>

namespace cg = cooperative_groups;

#define B_   256
#define H_   512
#define V_   16000
#define M_   32
#define SOS_ 1
#define EOS_ 2
#define INV_SCALE (1.0f/2048.0f)
#define NTHR 256

typedef _Float16 half_t;
typedef _Float16 f16x8 __attribute__((ext_vector_type(8)));
typedef _Float16 f16x4 __attribute__((ext_vector_type(4)));
typedef float    f32x4 __attribute__((ext_vector_type(4)));

struct Params {
    const float *sem_f, *emb;
    const float *b_ih0, *b_hh0, *b_ih1, *b_hh1, *fc_b;
    const float *W_ih0, *W_hh0, *W_ih1, *W_hh1, *fc_W;
    float *decoded, *logits, *mask;
    float *PRE, *h0, *h1;
    half_t *h0a, *h0b, *h1a, *h1b, *xa, *xb;
    float *pmax; int *pidx; int *inputs; int *finished;
    half_t *wi0a, *wi0b, *wh0a, *wh0b, *wi1a, *wi1b, *wh1a, *wh1b, *fca, *fcbp;
};

__device__ __forceinline__ void split_f32(float x, half_t& a, half_t& b) {
    a = (half_t)x;
    b = (half_t)((x - (float)a) * 2048.0f);
}

__device__ __forceinline__ void split_plane_dev(const float* __restrict__ src,
    half_t* __restrict__ hi, half_t* __restrict__ lo, int n4, int gidx, int gst)
{
    for (int i = gidx; i < n4; i += gst) {
        const float4 v = ((const float4*)src)[i];
        f16x4 a, b; half_t t0, t1;
        split_f32(v.x, t0, t1); a[0] = t0; b[0] = t1;
        split_f32(v.y, t0, t1); a[1] = t0; b[1] = t1;
        split_f32(v.z, t0, t1); a[2] = t0; b[2] = t1;
        split_f32(v.w, t0, t1); a[3] = t0; b[3] = t1;
        ((f16x4*)hi)[i] = a; ((f16x4*)lo)[i] = b;
    }
}

// ---------------------------------------------------------------------------
// Unified GEMM tile: OUT[128 rows x 64 cols], K=512, fp16x2 3-pass MFMA.
// 4 waves as 2x2; wave = 64 rows x 32 cols; rf=4, cf=2.
// A planes read from global; W tile (64 x 32-K slice, both planes) staged in LDS.
// ---------------------------------------------------------------------------

// ----- GRU variant: ct in [0,48) (ct<24 -> ih), rt in [0,2). Epilogue -> PRE.
__device__ void gru_tile(int ct, int rt,
    const half_t* __restrict__ Aia, const half_t* __restrict__ Aib,
    const half_t* __restrict__ Aha, const half_t* __restrict__ Ahb,
    const half_t* __restrict__ Wia, const half_t* __restrict__ Wib,
    const half_t* __restrict__ Wha, const half_t* __restrict__ Whb,
    const float* __restrict__ b_ih, const float* __restrict__ b_hh,
    float* __restrict__ PRE,
    half_t (*W0s)[40], half_t (*W1s)[40])
{
    const bool is_ih = (ct < 24);
    const int wrow0 = (is_ih ? ct : ct - 24) * 64;   // W/bias row offset
    const int row0  = rt * 128;
    const float*  bias = is_ih ? b_ih : b_hh;
    const half_t* Aa = is_ih ? Aia : Aha;
    const half_t* Ab = is_ih ? Aib : Ahb;
    const half_t* W0 = is_ih ? Wia : Wha;
    const half_t* W1 = is_ih ? Wib : Whb;

    const int tid  = threadIdx.x;
    const int wv   = tid >> 6;
    const int wr   = wv >> 1, wc = wv & 1;
    const int lane = tid & 63;
    const int ll   = lane & 15, lg = lane >> 4;
    const int sc   = tid >> 2;             // 0..63 staged W row
    const int sk   = (tid & 3) * 8;        // 0,8,16,24
    const half_t* wp0 = W0 + (size_t)(wrow0 + sc) * H_ + sk;
    const half_t* wp1 = W1 + (size_t)(wrow0 + sc) * H_ + sk;

    f32x4 accM[4][2] = {};
    f32x4 accC[4][2] = {};

    for (int k0 = 0; k0 < H_; k0 += 32) {
        const f16x8 s0 = *(const f16x8*)(wp0 + k0);
        const f16x8 s1 = *(const f16x8*)(wp1 + k0);
        __syncthreads();
        *(f16x8*)&W0s[sc][sk] = s0;
        *(f16x8*)&W1s[sc][sk] = s1;
        __syncthreads();

        f16x8 a0[4], a1[4];
#pragma unroll
        for (int rf = 0; rf < 4; ++rf) {
            const size_t off = ((size_t)(row0 + 64*wr + 16*rf + ll) << 9) + k0 + (lg << 3);
            a0[rf] = *(const f16x8*)(Aa + off);
            a1[rf] = *(const f16x8*)(Ab + off);
        }
#pragma unroll
        for (int cf = 0; cf < 2; ++cf) {
            const int c = 32*wc + 16*cf + ll;
            const f16x8 b0 = *(const f16x8*)&W0s[c][lg << 3];
            const f16x8 b1 = *(const f16x8*)&W1s[c][lg << 3];
#pragma unroll
            for (int rf = 0; rf < 4; ++rf) {
                accM[rf][cf] = __builtin_amdgcn_mfma_f32_16x16x32_f16(a0[rf], b0, accM[rf][cf], 0,0,0);
                accC[rf][cf] = __builtin_amdgcn_mfma_f32_16x16x32_f16(a0[rf], b1, accC[rf][cf], 0,0,0);
                accC[rf][cf] = __builtin_amdgcn_mfma_f32_16x16x32_f16(a1[rf], b0, accC[rf][cf], 0,0,0);
            }
        }
    }

#pragma unroll
    for (int cf = 0; cf < 2; ++cf) {
        const int cl = 32*wc + 16*cf + ll;           // 0..63
        const float bv = bias[wrow0 + cl];
        const int c = ct * 64 + cl;                  // 0..3071
#pragma unroll
        for (int rf = 0; rf < 4; ++rf) {
#pragma unroll
            for (int r = 0; r < 4; ++r) {
                const int row = row0 + 64*wr + 16*rf + lg*4 + r;
                PRE[(size_t)row * 3072 + c] = accM[rf][cf][r] + accC[rf][cf][r] * INV_SCALE + bv;
            }
        }
    }
}

// ----- FC variant: ct in [0,250), rt in [0,2). Epilogue -> logits + argmax partials.
__device__ void fc_tile(int ct, int rt,
    const half_t* __restrict__ Aa, const half_t* __restrict__ Ab,
    const half_t* __restrict__ W0, const half_t* __restrict__ W1,
    const float* __restrict__ fcb, const int* __restrict__ finished,
    float* __restrict__ logits, float* __restrict__ pmax, int* __restrict__ pidx,
    int t, half_t (*W0s)[40], half_t (*W1s)[40], float (*pmS)[2], int (*piS)[2])
{
    const int col0 = ct * 64;
    const int row0 = rt * 128;
    const int tid  = threadIdx.x;
    const int wv   = tid >> 6;
    const int wr   = wv >> 1, wc = wv & 1;
    const int lane = tid & 63;
    const int ll   = lane & 15, lg = lane >> 4;
    const int sc   = tid >> 2;
    const int sk   = (tid & 3) * 8;
    const half_t* wp0 = W0 + (size_t)(col0 + sc) * H_ + sk;
    const half_t* wp1 = W1 + (size_t)(col0 + sc) * H_ + sk;

    f32x4 accM[4][2] = {};
    f32x4 accC[4][2] = {};

    for (int k0 = 0; k0 < H_; k0 += 32) {
        const f16x8 s0 = *(const f16x8*)(wp0 + k0);
        const f16x8 s1 = *(const f16x8*)(wp1 + k0);
        __syncthreads();
        *(f16x8*)&W0s[sc][sk] = s0;
        *(f16x8*)&W1s[sc][sk] = s1;
        __syncthreads();

        f16x8 a0[4], a1[4];
#pragma unroll
        for (int rf = 0; rf < 4; ++rf) {
            const size_t off = ((size_t)(row0 + 64*wr + 16*rf + ll) << 9) + k0 + (lg << 3);
            a0[rf] = *(const f16x8*)(Aa + off);
            a1[rf] = *(const f16x8*)(Ab + off);
        }
#pragma unroll
        for (int cf = 0; cf < 2; ++cf) {
            const int c = 32*wc + 16*cf + ll;
            const f16x8 b0 = *(const f16x8*)&W0s[c][lg << 3];
            const f16x8 b1 = *(const f16x8*)&W1s[c][lg << 3];
#pragma unroll
            for (int rf = 0; rf < 4; ++rf) {
                accM[rf][cf] = __builtin_amdgcn_mfma_f32_16x16x32_f16(a0[rf], b0, accM[rf][cf], 0,0,0);
                accC[rf][cf] = __builtin_amdgcn_mfma_f32_16x16x32_f16(a0[rf], b1, accC[rf][cf], 0,0,0);
                accC[rf][cf] = __builtin_amdgcn_mfma_f32_16x16x32_f16(a1[rf], b0, accC[rf][cf], 0,0,0);
            }
        }
    }

    int fin[4][4];
    float bvv[4][4];
    int   bii[4][4];
#pragma unroll
    for (int rf = 0; rf < 4; ++rf)
#pragma unroll
        for (int r = 0; r < 4; ++r) {
            fin[rf][r] = finished[row0 + 64*wr + 16*rf + lg*4 + r];
            bvv[rf][r] = -INFINITY; bii[rf][r] = 0x7fffffff;
        }

#pragma unroll
    for (int cf = 0; cf < 2; ++cf) {
        const int col = col0 + 32*wc + 16*cf + ll;
        const float bv = fcb[col];
#pragma unroll
        for (int rf = 0; rf < 4; ++rf) {
#pragma unroll
            for (int r = 0; r < 4; ++r) {
                const int row = row0 + 64*wr + 16*rf + lg*4 + r;
                const float raw = accM[rf][cf][r] + accC[rf][cf][r] * INV_SCALE + bv;
                logits[((size_t)row * M_ + t) * V_ + col] = fin[rf][r] ? 0.0f : raw;
                if (raw > bvv[rf][r]) { bvv[rf][r] = raw; bii[rf][r] = col; } // cf asc
            }
        }
    }

#pragma unroll
    for (int rf = 0; rf < 4; ++rf) {
#pragma unroll
        for (int r = 0; r < 4; ++r) {
            float v = bvv[rf][r]; int ix = bii[rf][r];
#pragma unroll
            for (int m = 1; m < 16; m <<= 1) {
                const float ov = __shfl_xor(v, m);
                const int   oi = __shfl_xor(ix, m);
                if (ov > v || (ov == v && oi < ix)) { v = ov; ix = oi; }
            }
            if (ll == 0) {
                const int lr = 64*wr + 16*rf + lg*4 + r;   // 0..127
                pmS[lr][wc] = v; piS[lr][wc] = ix;
            }
        }
    }
    __syncthreads();
    if (tid < 128) {
        float v = pmS[tid][0]; int ix = piS[tid][0];
        const float v2 = pmS[tid][1]; const int i2 = piS[tid][1];
        if (v2 > v || (v2 == v && i2 < ix)) { v = v2; ix = i2; }
        pmax[(size_t)(row0 + tid) * 256 + ct] = v;
        pidx[(size_t)(row0 + tid) * 256 + ct] = ix;
    }
    __syncthreads();
}

// ----- gate elementwise (one h element) -----
__device__ __forceinline__ void gate_elem(const float* __restrict__ PRE,
    float* __restrict__ h, half_t* __restrict__ ha, half_t* __restrict__ hb,
    const int* __restrict__ finished, int idx)
{
    const int b = idx >> 9;
    const int j = idx & 511;
    if (finished[b]) return;
    const float* p = PRE + (size_t)b * 3072;
    const float ir = p[j],        iz = p[512 + j],  in_ = p[1024 + j];
    const float hr = p[1536 + j], hz = p[2048 + j], hn  = p[2560 + j];
    const float r = 1.0f / (1.0f + expf(-(ir + hr)));
    const float z = 1.0f / (1.0f + expf(-(iz + hz)));
    const float n = tanhf(in_ + r * hn);
    const float hv = (1.0f - z) * n + z * h[idx];
    h[idx] = hv;
    half_t a, bb; split_f32(hv, a, bb);
    ha[idx] = a; hb[idx] = bb;
}

// ----- finalize one row (256 threads) -----
__device__ void finalize_row(int b, const Params& p, int t,
                             float* sv, int* si, int* s_tok)
{
    const int tid = threadIdx.x;
    float v = -INFINITY; int ix = 0x7fffffff;
    if (tid < 250) { v = p.pmax[(size_t)b * 256 + tid]; ix = p.pidx[(size_t)b * 256 + tid]; }
    sv[tid] = v; si[tid] = ix;
    __syncthreads();
    for (int s = 128; s > 0; s >>= 1) {
        if (tid < s) {
            const float v2 = sv[tid + s]; const int i2 = si[tid + s];
            if (v2 > sv[tid] || (v2 == sv[tid] && i2 < si[tid])) { sv[tid] = v2; si[tid] = i2; }
        }
        __syncthreads();
    }
    if (tid == 0) {
        const int fin = p.finished[b];
        const int dec = si[0];
        p.decoded[b * M_ + t] = fin ? -1.0f : (float)dec;
        p.mask   [b * M_ + t] = fin ? 0.0f : 1.0f;
        int tok;
        if (!fin) { p.inputs[b] = dec; if (dec == EOS_) p.finished[b] = 1; tok = dec; }
        else tok = p.inputs[b];
        *s_tok = tok;
    }
    __syncthreads();
    const int tok = *s_tok;
    for (int j = tid; j < H_; j += NTHR) {
        const float v2 = p.emb[(size_t)tok * H_ + j];
        half_t a, bb; split_f32(v2, a, bb);
        p.xa[b * H_ + j] = a; p.xb[b * H_ + j] = bb;
    }
    __syncthreads();
}

// ---------------------------------------------------------------------------
// Persistent cooperative kernel: preamble + 32 steps, grid-stride phases.
// ---------------------------------------------------------------------------
__global__ __launch_bounds__(NTHR, 2)
void scan_coop(Params p)
{
    cg::grid_group grid = cg::this_grid();

    __shared__ half_t W0s[64][40];
    __shared__ half_t W1s[64][40];
    __shared__ float  red_f[256];
    __shared__ int    red_i[256];
    __shared__ int    s_tok;

    const int nblk = gridDim.x;
    const int blk  = blockIdx.x;
    const int tid  = threadIdx.x;
    const int gidx = blk * NTHR + tid;
    const int gst  = nblk * NTHR;

    // preamble: weight splits + state init
    split_plane_dev(p.W_ih0, p.wi0a, p.wi0b, (1536*512)/4, gidx, gst);
    split_plane_dev(p.W_hh0, p.wh0a, p.wh0b, (1536*512)/4, gidx, gst);
    split_plane_dev(p.W_ih1, p.wi1a, p.wi1b, (1536*512)/4, gidx, gst);
    split_plane_dev(p.W_hh1, p.wh1a, p.wh1b, (1536*512)/4, gidx, gst);
    split_plane_dev(p.fc_W,  p.fca,  p.fcbp, (V_*H_)/4,    gidx, gst);
    for (int i = gidx; i < B_ * H_; i += gst) {
        const float v = p.sem_f[i];
        p.h0[i] = v; p.h1[i] = v;
        half_t a, b; split_f32(v, a, b);
        p.h0a[i] = a; p.h0b[i] = b;
        p.h1a[i] = a; p.h1b[i] = b;
        const int j = i & (H_ - 1);
        const float xv = p.emb[SOS_ * H_ + j];
        half_t c, d; split_f32(xv, c, d);
        p.xa[i] = c; p.xb[i] = d;
    }
    for (int i = gidx; i < B_; i += gst) { p.inputs[i] = SOS_; p.finished[i] = 0; }
    grid.sync();

    for (int t = 0; t < M_; ++t) {
        // P1: GRU-0 pre-activations (96 tiles: ct 48 x rt 2)
        for (int tile = blk; tile < 96; tile += nblk)
            gru_tile(tile % 48, tile / 48, p.xa, p.xb, p.h0a, p.h0b,
                     p.wi0a, p.wi0b, p.wh0a, p.wh0b, p.b_ih0, p.b_hh0, p.PRE, W0s, W1s);
        grid.sync();
        // P2: gate 0
        for (int i = gidx; i < B_ * H_; i += gst)
            gate_elem(p.PRE, p.h0, p.h0a, p.h0b, p.finished, i);
        grid.sync();
        // P3: GRU-1 pre-activations
        for (int tile = blk; tile < 96; tile += nblk)
            gru_tile(tile % 48, tile / 48, p.h0a, p.h0b, p.h1a, p.h1b,
                     p.wi1a, p.wi1b, p.wh1a, p.wh1b, p.b_ih1, p.b_hh1, p.PRE, W0s, W1s);
        grid.sync();
        // P4: gate 1
        for (int i = gidx; i < B_ * H_; i += gst)
            gate_elem(p.PRE, p.h1, p.h1a, p.h1b, p.finished, i);
        grid.sync();
        // P5: FC + logits + argmax partials (500 tiles: ct 250 x rt 2)
        for (int tile = blk; tile < 500; tile += nblk)
            fc_tile(tile % 250, tile / 250, p.h1a, p.h1b, p.fca, p.fcbp, p.fc_b,
                    p.finished, p.logits, p.pmax, p.pidx, t, W0s, W1s,
                    (float(*)[2])red_f, (int(*)[2])red_i);
        grid.sync();
        // P6: finalize + next-x gather
        for (int b = blk; b < B_; b += nblk)
            finalize_row(b, p, t, red_f, red_i, &s_tok);
        grid.sync();
    }
}

// ---------------------------------------------------------------------------
// Fallback multi-kernel path (same math, separate launches)
// ---------------------------------------------------------------------------
__global__ __launch_bounds__(256)
void split_weights_k(const float* __restrict__ src, half_t* __restrict__ hi,
                     half_t* __restrict__ lo, int n4)
{
    const int i = blockIdx.x * 256 + threadIdx.x;
    if (i >= n4) return;
    const float4 v = ((const float4*)src)[i];
    f16x4 a, b; half_t t0, t1;
    split_f32(v.x, t0, t1); a[0] = t0; b[0] = t1;
    split_f32(v.y, t0, t1); a[1] = t0; b[1] = t1;
    split_f32(v.z, t0, t1); a[2] = t0; b[2] = t1;
    split_f32(v.w, t0, t1); a[3] = t0; b[3] = t1;
    ((f16x4*)hi)[i] = a; ((f16x4*)lo)[i] = b;
}

__global__ __launch_bounds__(256)
void init_k(Params p)
{
    const int i = blockIdx.x * 256 + threadIdx.x;
    if (i < B_ * H_) {
        const float v = p.sem_f[i];
        p.h0[i] = v; p.h1[i] = v;
        half_t a, b; split_f32(v, a, b);
        p.h0a[i] = a; p.h0b[i] = b;
        p.h1a[i] = a; p.h1b[i] = b;
        const int j = i & (H_ - 1);
        const float xv = p.emb[SOS_ * H_ + j];
        half_t c, d; split_f32(xv, c, d);
        p.xa[i] = c; p.xb[i] = d;
    }
    if (i < B_) { p.inputs[i] = SOS_; p.finished[i] = 0; }
}

__global__ __launch_bounds__(256)
void gru_k(const half_t* Aia, const half_t* Aib, const half_t* Aha, const half_t* Ahb,
           const half_t* Wia, const half_t* Wib, const half_t* Wha, const half_t* Whb,
           const float* b_ih, const float* b_hh, float* PRE)
{
    __shared__ half_t W0s[64][40];
    __shared__ half_t W1s[64][40];
    gru_tile(blockIdx.x, blockIdx.y, Aia, Aib, Aha, Ahb,
             Wia, Wib, Wha, Whb, b_ih, b_hh, PRE, W0s, W1s);
}

__global__ __launch_bounds__(256)
void gate_k(const float* PRE, float* h, half_t* ha, half_t* hb, const int* finished)
{
    gate_elem(PRE, h, ha, hb, finished, blockIdx.x * 256 + threadIdx.x);
}

__global__ __launch_bounds__(256)
void fc_k(const half_t* Aa, const half_t* Ab, const half_t* W0, const half_t* W1,
          const float* fcb, const int* finished, float* logits,
          float* pmax, int* pidx, int t)
{
    __shared__ half_t W0s[64][40];
    __shared__ half_t W1s[64][40];
    __shared__ float  pmS[128][2];
    __shared__ int    piS[128][2];
    fc_tile(blockIdx.x, blockIdx.y, Aa, Ab, W0, W1, fcb, finished,
            logits, pmax, pidx, t, W0s, W1s, pmS, piS);
}

__global__ __launch_bounds__(256)
void finalize_k(Params p, int t)
{
    __shared__ float sv[256];
    __shared__ int   si[256];
    __shared__ int   s_tok;
    finalize_row(blockIdx.x, p, t, sv, si, &s_tok);
}

// ---------------------------------------------------------------------------
extern "C" void kernel_launch(void* const* d_in, const int* in_sizes, int n_in,
                              void* d_out, int out_size, void* d_ws, size_t ws_size,
                              hipStream_t stream)
{
    Params p;
    p.sem_f = (const float*)d_in[0];
    p.emb   = (const float*)d_in[1];
    p.W_ih0 = (const float*)d_in[2];
    p.W_hh0 = (const float*)d_in[3];
    p.b_ih0 = (const float*)d_in[4];
    p.b_hh0 = (const float*)d_in[5];
    p.W_ih1 = (const float*)d_in[6];
    p.W_hh1 = (const float*)d_in[7];
    p.b_ih1 = (const float*)d_in[8];
    p.b_hh1 = (const float*)d_in[9];
    p.fc_W  = (const float*)d_in[10];
    p.fc_b  = (const float*)d_in[11];

    float* out = (float*)d_out;
    p.decoded = out;
    p.logits  = out + (size_t)B_ * M_;
    p.mask    = out + (size_t)B_ * M_ + (size_t)B_ * M_ * V_;

    float* ws = (float*)d_ws;
    p.PRE  = ws;                              // 786432
    p.h0   = ws + 786432;                     // 131072
    p.h1   = ws + 917504;                     // 131072
    p.h0a  = (half_t*)(ws + 1048576);         // 65536 f each
    p.h0b  = (half_t*)(ws + 1114112);
    p.h1a  = (half_t*)(ws + 1179648);
    p.h1b  = (half_t*)(ws + 1245184);
    p.xa   = (half_t*)(ws + 1310720);
    p.xb   = (half_t*)(ws + 1376256);
    p.pmax = ws + 1441792;                    // 256*256 = 65536
    p.pidx = (int*)(ws + 1507328);            // 65536
    p.inputs   = (int*)(ws + 1572864);        // 256
    p.finished = (int*)(ws + 1573120);        // 256
    p.wi0a = (half_t*)(ws + 1573376);         // each GRU plane 393216 f
    p.wi0b = (half_t*)(ws + 1966592);
    p.wh0a = (half_t*)(ws + 2359808);
    p.wh0b = (half_t*)(ws + 2753024);
    p.wi1a = (half_t*)(ws + 3146240);
    p.wi1b = (half_t*)(ws + 3539456);
    p.wh1a = (half_t*)(ws + 3932672);
    p.wh1b = (half_t*)(ws + 4325888);
    p.fca  = (half_t*)(ws + 4719104);         // 4096000 f each
    p.fcbp = (half_t*)(ws + 8815104);
    // total 12911104 floats = 51.6 MB

    // ---- try the cooperative persistent kernel, occupancy-sized ----
    int occ = 0;
    hipError_t oe = hipOccupancyMaxActiveBlocksPerMultiprocessor(&occ, scan_coop, NTHR, 0);
    hipError_t le = hipErrorUnknown;
    if (oe == hipSuccess && occ >= 1) {
        const int nblk = (occ >= 2) ? 512 : 256;
        void* args[] = { &p };
        le = hipLaunchCooperativeKernel((const void*)scan_coop, dim3(nblk), dim3(NTHR),
                                        args, 0, stream);
    }
    if (le == hipSuccess) return;

    // ---- fallback: multi-kernel sequence (identical math) ----
    const int nGru4 = (1536 * 512) / 4;
    const int nFc4  = (V_ * H_) / 4;
    split_weights_k<<<(nGru4 + 255) / 256, 256, 0, stream>>>(p.W_ih0, p.wi0a, p.wi0b, nGru4);
    split_weights_k<<<(nGru4 + 255) / 256, 256, 0, stream>>>(p.W_hh0, p.wh0a, p.wh0b, nGru4);
    split_weights_k<<<(nGru4 + 255) / 256, 256, 0, stream>>>(p.W_ih1, p.wi1a, p.wi1b, nGru4);
    split_weights_k<<<(nGru4 + 255) / 256, 256, 0, stream>>>(p.W_hh1, p.wh1a, p.wh1b, nGru4);
    split_weights_k<<<(nFc4 + 255) / 256, 256, 0, stream>>>(p.fc_W, p.fca, p.fcbp, nFc4);
    init_k<<<(B_ * H_ + 255) / 256, 256, 0, stream>>>(p);

    const dim3 gruGrid(48, 2);
    const dim3 fcGrid(250, 2);
    for (int t = 0; t < M_; ++t) {
        gru_k<<<gruGrid, 256, 0, stream>>>(p.xa, p.xb, p.h0a, p.h0b,
            p.wi0a, p.wi0b, p.wh0a, p.wh0b, p.b_ih0, p.b_hh0, p.PRE);
        gate_k<<<(B_ * H_) / 256, 256, 0, stream>>>(p.PRE, p.h0, p.h0a, p.h0b, p.finished);
        gru_k<<<gruGrid, 256, 0, stream>>>(p.h0a, p.h0b, p.h1a, p.h1b,
            p.wi1a, p.wi1b, p.wh1a, p.wh1b, p.b_ih1, p.b_hh1, p.PRE);
        gate_k<<<(B_ * H_) / 256, 256, 0, stream>>>(p.PRE, p.h1, p.h1a, p.h1b, p.finished);
        fc_k<<<fcGrid, 256, 0, stream>>>(p.h1a, p.h1b, p.fca, p.fcbp, p.fc_b,
            p.finished, p.logits, p.pmax, p.pidx, t);
        finalize_k<<<B_, 256, 0, stream>>>(p, t);
    }
}